// Round 5
// baseline (280.206 us; speedup 1.0000x reference)
//
#include <hip/hip_runtime.h>
#include <math.h>
#include <stdint.h>

#define ALPHA 0.2f

typedef __attribute__((ext_vector_type(8)))  short bf16x8;
typedef __attribute__((ext_vector_type(16))) float f32x16;

__device__ __forceinline__ uint32_t pack_bf16(float a, float b) {
    return ((__float_as_uint(a) + 0x8000u) >> 16) |
           ((__float_as_uint(b) + 0x8000u) & 0xFFFF0000u);
}

// ---------------------------------------------------------------------------
// Kernel 1: k_pre — fused k_wh + k_adjb (block-branched grid). Unchanged
// (passed rounds 3 and 4).
// ---------------------------------------------------------------------------
__global__ __launch_bounds__(512) void k_pre(const float* __restrict__ x,
                                             const float* __restrict__ W,
                                             const float* __restrict__ a,
                                             const float* __restrict__ adj,
                                             uint4* __restrict__ Whf,
                                             float* __restrict__ Wh1,
                                             float* __restrict__ Wh2,
                                             unsigned char* __restrict__ adjq) {
    __shared__ float xs[16 * 512];        // 32 KB
    __shared__ float Wv[128 * 68];        // 34.8 KB

    if (blockIdx.x >= 512) {
        // ---- adjb part: 256 blocks x 512 threads, idx 0..131071 ----
        int idx = (blockIdx.x - 512) * 512 + threadIdx.x;
        int i   = idx >> 7;
        int pos = idx & 127;                            // jg
        const float4* a4 = (const float4*)adj + idx * 2;
        float4 v0 = a4[0], v1 = a4[1];
        unsigned int by = 0;
        by |= (v0.x > 0.f) ? 1u : 0u;
        by |= (v0.y > 0.f) ? 2u : 0u;
        by |= (v0.z > 0.f) ? 4u : 0u;
        by |= (v0.w > 0.f) ? 8u : 0u;
        by |= (v1.x > 0.f) ? 16u : 0u;
        by |= (v1.y > 0.f) ? 32u : 0u;
        by |= (v1.z > 0.f) ? 64u : 0u;
        by |= (v1.w > 0.f) ? 128u : 0u;
        adjq[(i << 7) + ((pos & 1) << 6) + (((pos >> 1) & 1) << 5) + (pos >> 2)] =
            (unsigned char)by;
        return;
    }

    // ---- wh part ----
    const int tid = threadIdx.x;
    const int b   = blockIdx.x & 7;
    const int jt  = blockIdx.x >> 3;      // 0..63 (16-row tiles)

    const float4* xg4 = (const float4*)(x + (size_t)(b * 1024 + jt * 16) * 512);
    #pragma unroll
    for (int i = 0; i < 4; ++i) {
        int    idx = tid + i * 512;       // 0..2047
        float4 v   = xg4[idx];
        int jl  = idx >> 7;
        int rem = idx & 127;
        int f   = rem >> 1;
        int tq  = rem & 1;
        int kk  = f ^ ((jl >> 2) << 2);
        float* dst = &xs[jl * 512 + (tq * 4) * 64 + kk];
        dst[0]   = v.x;
        dst[64]  = v.y;
        dst[128] = v.z;
        dst[192] = v.w;
    }
    const float4* Wg4 = (const float4*)W;
    #pragma unroll
    for (int i = 0; i < 4; ++i) {
        int    idx = tid + i * 512;       // 0..2047
        float4 v   = Wg4[idx];
        int k  = idx >> 5;
        int o0 = (idx & 31) * 4;
        #pragma unroll
        for (int c = 0; c < 4; ++c) {
            int o   = o0 + c;
            int adr = o * 68 + ((((k >> 2) ^ ((o >> 3) & 7)) << 2) | (k & 3));
            Wv[adr] = (&v.x)[c];
        }
    }
    __syncthreads();

    const int w  = tid >> 6;              // wave = t (0..7)
    const int l  = tid & 63;
    const int q  = l >> 4;
    const int om = l & 15;
    const int t  = w;

    float acc[4][8];
    #pragma unroll
    for (int jj = 0; jj < 4; ++jj)
        #pragma unroll
        for (int nt = 0; nt < 8; ++nt) acc[jj][nt] = 0.f;

    for (int kc = 0; kc < 64; kc += 4) {
        float4 xv[4], wv[8];
        const int kx = kc ^ (q << 2);
        #pragma unroll
        for (int jj = 0; jj < 4; ++jj)
            xv[jj] = *(const float4*)&xs[(q * 4 + jj) * 512 + t * 64 + kx];
        #pragma unroll
        for (int nt = 0; nt < 8; ++nt) {
            int og  = nt * 16 + om;
            int grp = (kc >> 2) ^ ((nt * 2 + (om >> 3)) & 7);
            wv[nt]  = *(const float4*)&Wv[og * 68 + grp * 4];
        }
        #pragma unroll
        for (int jj = 0; jj < 4; ++jj) {
            #pragma unroll
            for (int nt = 0; nt < 8; ++nt) {
                float s = acc[jj][nt];
                s = fmaf(xv[jj].x, wv[nt].x, s);
                s = fmaf(xv[jj].y, wv[nt].y, s);
                s = fmaf(xv[jj].z, wv[nt].z, s);
                s = fmaf(xv[jj].w, wv[nt].w, s);
                acc[jj][nt] = s;
            }
        }
    }

    const int bt = b * 8 + t;

    float a1v[8], a2v[8];
    #pragma unroll
    for (int nt = 0; nt < 8; ++nt) {
        a1v[nt] = a[nt * 16 + om];
        a2v[nt] = a[128 + nt * 16 + om];
    }
    #pragma unroll
    for (int jj = 0; jj < 4; ++jj) {
        float s1 = 0.f, s2 = 0.f;
        #pragma unroll
        for (int nt = 0; nt < 8; ++nt) {
            s1 = fmaf(acc[jj][nt], a1v[nt], s1);
            s2 = fmaf(acc[jj][nt], a2v[nt], s2);
        }
        #pragma unroll
        for (int off = 1; off < 16; off <<= 1) {
            s1 += __shfl_xor(s1, off);
            s2 += __shfl_xor(s2, off);
        }
        if (om == 0) {
            int j = jt * 16 + q * 4 + jj;
            Wh1[bt * 1024 + j] = s1;
            Wh2[bt * 1024 + j] = s2;
        }
    }

    // 32x32x16 B-frag store
    #pragma unroll
    for (int nt = 0; nt < 8; ++nt) {
        uint2 st;
        st.x = pack_bf16(acc[0][nt], acc[1][nt]);
        st.y = pack_bf16(acc[2][nt], acc[3][nt]);
        int    lane2 = ((q >> 1) << 5) | ((nt & 1) << 4) | om;
        size_t fidx  = ((size_t)(bt * 4 + (nt >> 1)) * 64 + jt) * 64 + lane2;
        char*  p     = (char*)(Whf + fidx) + ((q & 1) << 3);
        *(uint2*)p = st;
    }
}

// ---------------------------------------------------------------------------
// Kernel 2: k_agg — ROUND-14: barrier-free aggregation at DEFAULT launch
// bounds. This is EXACTLY the round-3 kernel (which PASSED) with the single
// token (256,2) -> (256):
//   r10 (256,4): VGPR capped 64  -> spill (682 MB scratch writes, 345 us)
//   r12 (256,2): VGPR capped 128 -> spill (455 MB, 250 us)
//   r13 gload_lds: non-provably-uniform LDS dest -> 256 VGPR balloon (156 MB)
//   r14 (256):   allocator free -> expect ~170-200 VGPR, ZERO scratch,
//                8 waves/CU (same as round-0) with ZERO in-loop barriers
//                (round-0's diagnosed stall was the 8 barrier drains).
// B-fragments from global: per-XCD working set 2 MB (L2-fit); all 4 waves of
// a block issue IDENTICAL q addresses (w-independent) -> L1 serves 3 of 4.
// Kill criterion: VGPR>=256 + WRITE>>33MB -> balloon intrinsic -> revert to
// round-0 structure next round.
// Layouts: A idx=lane&31, k=(lane>>5)*8+e; D col=lane&31,
// row=(reg&3)+8*(reg>>2)+4*(lane>>5). Grid 512: blockIdx=((itile*8+t)*8+b).
// ---------------------------------------------------------------------------
__global__ __launch_bounds__(256) void k_agg(const uint4* __restrict__ Whf,
                                             const float* __restrict__ Wh1,
                                             const float* __restrict__ Wh2,
                                             const unsigned char* __restrict__ adjq,
                                             float* __restrict__ out) {
    __shared__ __attribute__((aligned(16))) float efsE[1024];   // 4 KB
    __shared__ __attribute__((aligned(16))) float efsF[1024];   // 4 KB
    __shared__ float wh1s[128];
    __shared__ float m2s[4];

    const int tid   = threadIdx.x;
    const int b     = blockIdx.x & 7;
    const int t     = (blockIdx.x >> 3) & 7;
    const int itile = blockIdx.x >> 6;            // 0..7
    const int bt    = b * 8 + t;
    const int i0    = itile * 128;

    const int w   = tid >> 6;                     // wave 0..3 (row group)
    const int l   = tid & 63;
    const int col = l & 31;
    const int g   = l >> 5;                       // k-half group
    const int row = w * 32 + col;                 // block-local i-row

    const uint4* plane = Whf + (size_t)bt * 16384;

    // adj mask regs: 64 B at (i0+row)*128 + g*64
    const uint4* ap = (const uint4*)(adjq + ((size_t)(i0 + row) << 7) + (g << 6));
    uint4 am[4];
    #pragma unroll
    for (int f = 0; f < 4; ++f) am[f] = ap[f];

    // stage E/F (separate fp32) + running max of h2; Wh1 slice
    const float* wh2g = Wh2 + bt * 1024;
    float mx = -1e30f;
    #pragma unroll
    for (int rep = 0; rep < 4; ++rep) {
        int   j  = tid + rep * 256;
        float h2 = wh2g[j];
        efsE[j] = __expf(h2);
        efsF[j] = __expf(ALPHA * h2);
        mx = fmaxf(mx, h2);
    }
    #pragma unroll
    for (int off = 1; off < 64; off <<= 1) mx = fmaxf(mx, __shfl_xor(mx, off));
    if (l == 0) m2s[w] = mx;
    if (tid < 128) wh1s[tid] = Wh1[bt * 1024 + i0 + tid];
    __syncthreads();                              // the ONLY barrier

    const float M2 = fmaxf(fmaxf(m2s[0], m2s[1]), fmaxf(m2s[2], m2s[3]));
    const float h1 = wh1s[row];
    const float e0 = h1 + M2;
    const float mp = fmaxf(e0, ALPHA * e0);       // both products <= 1
    const float Af = __expf(h1 - mp);
    const float Bf = __expf(ALPHA * h1 - mp);

    f32x16 acc[4];
    #pragma unroll
    for (int nt2 = 0; nt2 < 4; ++nt2)
        #pragma unroll
        for (int r = 0; r < 16; ++r) acc[nt2][r] = 0.f;
    float sacc = 0.f;                             // fp32 row-sum (softmax denom)

    #pragma unroll
    for (int u = 0; u < 8; ++u) {
        #pragma unroll
        for (int ts = 0; ts < 8; ++ts) {          // 16-j MFMA slice
            const int step = u * 8 + ts;

            // B-fragments straight from global (L1/L2-resident)
            union { uint4 u4; bf16x8 v; } q0, q1, q2, q3;
            q0.u4 = plane[(0 * 64 + step) * 64 + l];
            q1.u4 = plane[(1 * 64 + step) * 64 + l];
            q2.u4 = plane[(2 * 64 + step) * 64 + l];
            q3.u4 = plane[(3 * 64 + step) * 64 + l];

            // adj byte (static select after full unroll)
            const int      pe = (ts & 1) * 32 + u * 4 + (ts >> 1);
            const uint4    av = am[pe >> 4];
            const int      cc = (pe >> 2) & 3;
            const uint32_t cw = (cc == 0) ? av.x : (cc == 1) ? av.y
                               : (cc == 2) ? av.z : av.w;
            const uint32_t by = (cw >> ((pe & 3) * 8)) & 0xFFu;

            const int jb = u * 128 + ts * 16 + g * 8;

            union { uint32_t u32[4]; bf16x8 v; } pk;

            // half A: j 0..3 of this slice
            {
                float4 E0 = *(const float4*)&efsE[jb];
                float4 F0 = *(const float4*)&efsF[jb];
                float p0 = fmaxf(Af * E0.x, Bf * F0.x) * (float)((by >> 0) & 1u);
                float p1 = fmaxf(Af * E0.y, Bf * F0.y) * (float)((by >> 1) & 1u);
                float p2 = fmaxf(Af * E0.z, Bf * F0.z) * (float)((by >> 2) & 1u);
                float p3 = fmaxf(Af * E0.w, Bf * F0.w) * (float)((by >> 3) & 1u);
                sacc += (p0 + p1) + (p2 + p3);
                pk.u32[0] = pack_bf16(p0, p1);
                pk.u32[1] = pack_bf16(p2, p3);
            }
            // half B: j 4..7
            {
                float4 E1 = *(const float4*)&efsE[jb + 4];
                float4 F1 = *(const float4*)&efsF[jb + 4];
                float p4 = fmaxf(Af * E1.x, Bf * F1.x) * (float)((by >> 4) & 1u);
                float p5 = fmaxf(Af * E1.y, Bf * F1.y) * (float)((by >> 5) & 1u);
                float p6 = fmaxf(Af * E1.z, Bf * F1.z) * (float)((by >> 6) & 1u);
                float p7 = fmaxf(Af * E1.w, Bf * F1.w) * (float)((by >> 7) & 1u);
                sacc += (p4 + p5) + (p6 + p7);
                pk.u32[2] = pack_bf16(p4, p5);
                pk.u32[3] = pack_bf16(p6, p7);
            }

            acc[0] = __builtin_amdgcn_mfma_f32_32x32x16_bf16(pk.v, q0.v, acc[0], 0, 0, 0);
            acc[1] = __builtin_amdgcn_mfma_f32_32x32x16_bf16(pk.v, q1.v, acc[1], 0, 0, 0);
            acc[2] = __builtin_amdgcn_mfma_f32_32x32x16_bf16(pk.v, q2.v, acc[2], 0, 0, 0);
            acc[3] = __builtin_amdgcn_mfma_f32_32x32x16_bf16(pk.v, q3.v, acc[3], 0, 0, 0);
        }
    }

    // denom: lanes rl and rl+32 jointly cover row rl's j-range
    float tot = sacc + __shfl_xor(sacc, 32);      // lane c & c+32 -> denom(row c)

    // epilogue: D rows r = (reg&3)+8*(reg>>2)+4*g
    float* og = out + ((size_t)(b * 1024 + i0 + w * 32)) * 1024 + t;
    #pragma unroll
    for (int reg = 0; reg < 16; ++reg) {
        const int   r    = (reg & 3) + 8 * (reg >> 2) + 4 * g;
        const float linv = 1.0f / __shfl(tot, r); // denom lives at lane r (and r+32)
        #pragma unroll
        for (int nt2 = 0; nt2 < 4; ++nt2) {
            float v = acc[nt2][reg] * linv;
            v = v > 0.f ? v : __expf(v) - 1.f;
            og[(size_t)r * 1024 + (nt2 * 32 + col) * 8] = v;
        }
    }
}

// ---------------------------------------------------------------------------
extern "C" void kernel_launch(void* const* d_in, const int* in_sizes, int n_in,
                              void* d_out, int out_size, void* d_ws, size_t ws_size,
                              hipStream_t stream) {
    const float* x   = (const float*)d_in[0];   // (8,1024,64,8)
    const float* adj = (const float*)d_in[1];   // (1024,1024)
    const float* W   = (const float*)d_in[2];   // (64,128)
    const float* a   = (const float*)d_in[3];   // (256,1)
    float* out = (float*)d_out;                 // (8,1024,128,8)

    uint4*         Whf  = (uint4*)d_ws;                        // 1048576 uint4 = 16 MB
    float*         Wh1  = (float*)(Whf + 1048576);             // 65536 f
    float*         Wh2  = Wh1 + 65536;                         // 65536 f
    unsigned char* adjq = (unsigned char*)(Wh2 + 65536);       // 131072 B

    k_pre<<<768, 512, 0, stream>>>(x, W, a, adj, Whf, Wh1, Wh2, adjq);
    k_agg<<<512, 256, 0, stream>>>(Whf, Wh1, Wh2, adjq, out);
}

// Round 6
// 140.976 us; speedup vs baseline: 1.9876x; 1.9876x over previous
//
#include <hip/hip_runtime.h>
#include <math.h>
#include <stdint.h>

#define ALPHA 0.2f

typedef __attribute__((ext_vector_type(8)))  short bf16x8;
typedef __attribute__((ext_vector_type(4)))  float f32x4;
typedef __attribute__((ext_vector_type(16))) float f32x16;

__device__ __forceinline__ uint32_t pack_bf16(float a, float b) {
    return ((__float_as_uint(a) + 0x8000u) >> 16) |
           ((__float_as_uint(b) + 0x8000u) & 0xFFFF0000u);
}

// ---------------------------------------------------------------------------
// Kernel 1: k_pre — fused k_wh + k_adjb (block-branched grid). Verified
// passing (rounds 3-5); fusion saves ~10 us of launch overhead vs round-0's
// separate k_wh/k_adjb.
// ---------------------------------------------------------------------------
__global__ __launch_bounds__(512) void k_pre(const float* __restrict__ x,
                                             const float* __restrict__ W,
                                             const float* __restrict__ a,
                                             const float* __restrict__ adj,
                                             uint4* __restrict__ Whf,
                                             float* __restrict__ Wh1,
                                             float* __restrict__ Wh2,
                                             unsigned char* __restrict__ adjq) {
    __shared__ float xs[16 * 512];        // 32 KB
    __shared__ float Wv[128 * 68];        // 34.8 KB

    if (blockIdx.x >= 512) {
        // ---- adjb part: 256 blocks x 512 threads, idx 0..131071 ----
        int idx = (blockIdx.x - 512) * 512 + threadIdx.x;
        int i   = idx >> 7;
        int pos = idx & 127;                            // jg
        const float4* a4 = (const float4*)adj + idx * 2;
        float4 v0 = a4[0], v1 = a4[1];
        unsigned int by = 0;
        by |= (v0.x > 0.f) ? 1u : 0u;
        by |= (v0.y > 0.f) ? 2u : 0u;
        by |= (v0.z > 0.f) ? 4u : 0u;
        by |= (v0.w > 0.f) ? 8u : 0u;
        by |= (v1.x > 0.f) ? 16u : 0u;
        by |= (v1.y > 0.f) ? 32u : 0u;
        by |= (v1.z > 0.f) ? 64u : 0u;
        by |= (v1.w > 0.f) ? 128u : 0u;
        adjq[(i << 7) + ((pos & 1) << 6) + (((pos >> 1) & 1) << 5) + (pos >> 2)] =
            (unsigned char)by;
        return;
    }

    // ---- wh part ----
    const int tid = threadIdx.x;
    const int b   = blockIdx.x & 7;
    const int jt  = blockIdx.x >> 3;      // 0..63 (16-row tiles)

    const float4* xg4 = (const float4*)(x + (size_t)(b * 1024 + jt * 16) * 512);
    #pragma unroll
    for (int i = 0; i < 4; ++i) {
        int    idx = tid + i * 512;       // 0..2047
        float4 v   = xg4[idx];
        int jl  = idx >> 7;
        int rem = idx & 127;
        int f   = rem >> 1;
        int tq  = rem & 1;
        int kk  = f ^ ((jl >> 2) << 2);
        float* dst = &xs[jl * 512 + (tq * 4) * 64 + kk];
        dst[0]   = v.x;
        dst[64]  = v.y;
        dst[128] = v.z;
        dst[192] = v.w;
    }
    const float4* Wg4 = (const float4*)W;
    #pragma unroll
    for (int i = 0; i < 4; ++i) {
        int    idx = tid + i * 512;       // 0..2047
        float4 v   = Wg4[idx];
        int k  = idx >> 5;
        int o0 = (idx & 31) * 4;
        #pragma unroll
        for (int c = 0; c < 4; ++c) {
            int o   = o0 + c;
            int adr = o * 68 + ((((k >> 2) ^ ((o >> 3) & 7)) << 2) | (k & 3));
            Wv[adr] = (&v.x)[c];
        }
    }
    __syncthreads();

    const int w  = tid >> 6;              // wave = t (0..7)
    const int l  = tid & 63;
    const int q  = l >> 4;
    const int om = l & 15;
    const int t  = w;

    float acc[4][8];
    #pragma unroll
    for (int jj = 0; jj < 4; ++jj)
        #pragma unroll
        for (int nt = 0; nt < 8; ++nt) acc[jj][nt] = 0.f;

    for (int kc = 0; kc < 64; kc += 4) {
        float4 xv[4], wv[8];
        const int kx = kc ^ (q << 2);
        #pragma unroll
        for (int jj = 0; jj < 4; ++jj)
            xv[jj] = *(const float4*)&xs[(q * 4 + jj) * 512 + t * 64 + kx];
        #pragma unroll
        for (int nt = 0; nt < 8; ++nt) {
            int og  = nt * 16 + om;
            int grp = (kc >> 2) ^ ((nt * 2 + (om >> 3)) & 7);
            wv[nt]  = *(const float4*)&Wv[og * 68 + grp * 4];
        }
        #pragma unroll
        for (int jj = 0; jj < 4; ++jj) {
            #pragma unroll
            for (int nt = 0; nt < 8; ++nt) {
                float s = acc[jj][nt];
                s = fmaf(xv[jj].x, wv[nt].x, s);
                s = fmaf(xv[jj].y, wv[nt].y, s);
                s = fmaf(xv[jj].z, wv[nt].z, s);
                s = fmaf(xv[jj].w, wv[nt].w, s);
                acc[jj][nt] = s;
            }
        }
    }

    const int bt = b * 8 + t;

    float a1v[8], a2v[8];
    #pragma unroll
    for (int nt = 0; nt < 8; ++nt) {
        a1v[nt] = a[nt * 16 + om];
        a2v[nt] = a[128 + nt * 16 + om];
    }
    #pragma unroll
    for (int jj = 0; jj < 4; ++jj) {
        float s1 = 0.f, s2 = 0.f;
        #pragma unroll
        for (int nt = 0; nt < 8; ++nt) {
            s1 = fmaf(acc[jj][nt], a1v[nt], s1);
            s2 = fmaf(acc[jj][nt], a2v[nt], s2);
        }
        #pragma unroll
        for (int off = 1; off < 16; off <<= 1) {
            s1 += __shfl_xor(s1, off);
            s2 += __shfl_xor(s2, off);
        }
        if (om == 0) {
            int j = jt * 16 + q * 4 + jj;
            Wh1[bt * 1024 + j] = s1;
            Wh2[bt * 1024 + j] = s2;
        }
    }

    // 32x32x16 B-frag store
    #pragma unroll
    for (int nt = 0; nt < 8; ++nt) {
        uint2 st;
        st.x = pack_bf16(acc[0][nt], acc[1][nt]);
        st.y = pack_bf16(acc[2][nt], acc[3][nt]);
        int    lane2 = ((q >> 1) << 5) | ((nt & 1) << 4) | om;
        size_t fidx  = ((size_t)(bt * 4 + (nt >> 1)) * 64 + jt) * 64 + lane2;
        char*  p     = (char*)(Whf + fidx) + ((q & 1) << 3);
        *(uint2*)p = st;
    }
}

// ---------------------------------------------------------------------------
// Kernel 2: k_agg — ROUND-15: EXACT round-0 structure restored (proven
// 54 us, 88 VGPR, zero scratch). The barrier-free rewrite is abandoned:
// three configurations all spilled (r10 64-cap/682MB, r12 128-cap/455MB,
// r14 unbounded saturated at 256/168MB) — the register balloon is intrinsic
// to a fully-unrolled 64-step loop with 4 in-flight global loads + 64 acc
// AGPRs. The pf[]-register + ds_write double-buffer staging below keeps the
// live set at 88 VGPR; the 8 per-superstep barriers cost ~20% but do not
// spill. Do NOT touch this kernel's structure without a -Rpass resource
// check first.
// Layouts (verified): A idx=lane&31, k=(lane>>5)*8+e; D col=lane&31,
// row=(reg&3)+8*(reg>>2)+4*(lane>>5); l_i via ones-MFMA.
// Grid 512: blockIdx = ((itile*8 + t)*8 + b) -> XCD = b.
// ---------------------------------------------------------------------------
__global__ __launch_bounds__(256) void k_agg(const uint4* __restrict__ Whf,
                                             const float* __restrict__ Wh1,
                                             const float* __restrict__ Wh2,
                                             const unsigned char* __restrict__ adjq,
                                             float* __restrict__ out) {
    __shared__ __attribute__((aligned(16))) uint4 bstage[2][2048];  // 64 KB
    __shared__ __attribute__((aligned(16))) float efsE[1024];       // 4 KB
    __shared__ __attribute__((aligned(16))) float efsF[1024];       // 4 KB
    __shared__ float wh1s[128];
    __shared__ float m2s[4];

    const int tid   = threadIdx.x;
    const int b     = blockIdx.x & 7;
    const int t     = (blockIdx.x >> 3) & 7;
    const int itile = blockIdx.x >> 6;            // 0..7
    const int bt    = b * 8 + t;
    const int i0    = itile * 128;

    const int w   = tid >> 6;                     // wave 0..3 (= ntile chunk)
    const int l   = tid & 63;
    const int col = l & 31;
    const int g   = l >> 5;                       // k-half group
    const int row = w * 32 + col;                 // block-local i-row

    const uint4* plane = Whf + (size_t)bt * 16384;

    // prefetch superstep 0 (kf 0..7 of this wave's ntile chunk)
    uint4 pf[8];
    #pragma unroll
    for (int f = 0; f < 8; ++f) pf[f] = plane[(w * 64 + f) * 64 + l];

    // adj mask regs: 64 B at (i0+row)*128 + g*64
    const uint4* ap = (const uint4*)(adjq + ((size_t)(i0 + row) << 7) + (g << 6));
    uint4 am[4];
    #pragma unroll
    for (int f = 0; f < 4; ++f) am[f] = ap[f];

    // stage E/F (separate fp32) + running max of h2; Wh1 slice
    const float* wh2g = Wh2 + bt * 1024;
    float mx = -1e30f;
    #pragma unroll
    for (int rep = 0; rep < 4; ++rep) {
        int   j  = tid + rep * 256;
        float h2 = wh2g[j];
        efsE[j] = __expf(h2);
        efsF[j] = __expf(ALPHA * h2);
        mx = fmaxf(mx, h2);
    }
    #pragma unroll
    for (int off = 1; off < 64; off <<= 1) mx = fmaxf(mx, __shfl_xor(mx, off));
    if (l == 0) m2s[w] = mx;
    if (tid < 128) wh1s[tid] = Wh1[bt * 1024 + i0 + tid];

    #pragma unroll
    for (int f = 0; f < 8; ++f) bstage[0][(w * 8 + f) * 64 + l] = pf[f];
    __syncthreads();

    const float M2 = fmaxf(fmaxf(m2s[0], m2s[1]), fmaxf(m2s[2], m2s[3]));
    const float h1 = wh1s[row];
    const float e0 = h1 + M2;
    const float mp = fmaxf(e0, ALPHA * e0);       // both products <= 1
    const float Af = __expf(h1 - mp);
    const float Bf = __expf(ALPHA * h1 - mp);

    f32x16 acc[4];
    #pragma unroll
    for (int nt2 = 0; nt2 < 4; ++nt2)
        #pragma unroll
        for (int r = 0; r < 16; ++r) acc[nt2][r] = 0.f;
    f32x16 accl;
    #pragma unroll
    for (int r = 0; r < 16; ++r) accl[r] = 0.f;

    bf16x8 ones;
    #pragma unroll
    for (int i = 0; i < 8; ++i) ones[i] = (short)0x3F80;

    #pragma unroll
    for (int u = 0; u < 8; ++u) {
        if (u + 1 < 8) {
            #pragma unroll
            for (int f = 0; f < 8; ++f)
                pf[f] = plane[(w * 64 + (u + 1) * 8 + f) * 64 + l];
        }

        #pragma unroll
        for (int ts = 0; ts < 8; ++ts) {          // 16-j MFMA slice
            const int jb = u * 128 + ts * 16 + g * 8;
            float4 E0 = *(const float4*)&efsE[jb];
            float4 E1 = *(const float4*)&efsE[jb + 4];
            float4 F0 = *(const float4*)&efsF[jb];
            float4 F1 = *(const float4*)&efsF[jb + 4];

            // adj byte (static select after full unroll)
            const int      pe = (ts & 1) * 32 + u * 4 + (ts >> 1);
            const uint4    av = am[pe >> 4];
            const int      cc = (pe >> 2) & 3;
            const uint32_t cw = (cc == 0) ? av.x : (cc == 1) ? av.y
                               : (cc == 2) ? av.z : av.w;
            const uint32_t by = (cw >> ((pe & 3) * 8)) & 0xFFu;

            float p[8];
            p[0] = fmaxf(Af * E0.x, Bf * F0.x) * (float)((by >> 0) & 1u);
            p[1] = fmaxf(Af * E0.y, Bf * F0.y) * (float)((by >> 1) & 1u);
            p[2] = fmaxf(Af * E0.z, Bf * F0.z) * (float)((by >> 2) & 1u);
            p[3] = fmaxf(Af * E0.w, Bf * F0.w) * (float)((by >> 3) & 1u);
            p[4] = fmaxf(Af * E1.x, Bf * F1.x) * (float)((by >> 4) & 1u);
            p[5] = fmaxf(Af * E1.y, Bf * F1.y) * (float)((by >> 5) & 1u);
            p[6] = fmaxf(Af * E1.z, Bf * F1.z) * (float)((by >> 6) & 1u);
            p[7] = fmaxf(Af * E1.w, Bf * F1.w) * (float)((by >> 7) & 1u);

            union { uint32_t u32[4]; bf16x8 v; } pk;
            #pragma unroll
            for (int r = 0; r < 4; ++r)
                pk.u32[r] = pack_bf16(p[2 * r], p[2 * r + 1]);

            #pragma unroll
            for (int nt2 = 0; nt2 < 4; ++nt2) {
                union { uint4 u4; bf16x8 v; } br;
                br.u4 = bstage[u & 1][(nt2 * 8 + ts) * 64 + l];
                acc[nt2] = __builtin_amdgcn_mfma_f32_32x32x16_bf16(
                    pk.v, br.v, acc[nt2], 0, 0, 0);
            }
            accl = __builtin_amdgcn_mfma_f32_32x32x16_bf16(
                pk.v, ones, accl, 0, 0, 0);
        }

        if (u + 1 < 8) {
            #pragma unroll
            for (int f = 0; f < 8; ++f)
                bstage[(u + 1) & 1][(w * 8 + f) * 64 + l] = pf[f];
        }
        __syncthreads();
    }

    // epilogue: D rows r = (reg&3)+8*(reg>>2)+4*g; accl rows identical
    float* og = out + ((size_t)(b * 1024 + i0 + w * 32)) * 1024 + t;
    #pragma unroll
    for (int reg = 0; reg < 16; ++reg) {
        const int   r    = (reg & 3) + 8 * (reg >> 2) + 4 * g;
        const float linv = 1.0f / accl[reg];
        #pragma unroll
        for (int nt2 = 0; nt2 < 4; ++nt2) {
            float v = acc[nt2][reg] * linv;
            v = v > 0.f ? v : __expf(v) - 1.f;
            og[(size_t)r * 1024 + (nt2 * 32 + col) * 8] = v;
        }
    }
}

// ---------------------------------------------------------------------------
extern "C" void kernel_launch(void* const* d_in, const int* in_sizes, int n_in,
                              void* d_out, int out_size, void* d_ws, size_t ws_size,
                              hipStream_t stream) {
    const float* x   = (const float*)d_in[0];   // (8,1024,64,8)
    const float* adj = (const float*)d_in[1];   // (1024,1024)
    const float* W   = (const float*)d_in[2];   // (64,128)
    const float* a   = (const float*)d_in[3];   // (256,1)
    float* out = (float*)d_out;                 // (8,1024,128,8)

    uint4*         Whf  = (uint4*)d_ws;                        // 1048576 uint4 = 16 MB
    float*         Wh1  = (float*)(Whf + 1048576);             // 65536 f
    float*         Wh2  = Wh1 + 65536;                         // 65536 f
    unsigned char* adjq = (unsigned char*)(Wh2 + 65536);       // 131072 B

    k_pre<<<768, 512, 0, stream>>>(x, W, a, adj, Whf, Wh1, Wh2, adjq);
    k_agg<<<512, 256, 0, stream>>>(Whf, Wh1, Wh2, adjq, out);
}